// Round 8
// baseline (930.182 us; speedup 1.0000x reference)
//
#include <hip/hip_runtime.h>
#include <type_traits>

#define N_TOK 65536
#define K_CODE 8192
#define D_DIM 64

constexpr float DECAY = 0.9f;
constexpr float OMD = 0.1f;   // 1 - DECAY
constexpr float EPS = 1e-5f;

// ---- output layout (floats), per reference return order ----
constexpr int OUT_QE = 0;
constexpr int OUT_W  = 1;
constexpr int OUT_CS = 1 + K_CODE * D_DIM;
constexpr int OUT_EA = OUT_CS + K_CODE;

// ---- workspace layout (floats) ----
constexpr int WS_QE     = 0;
constexpr int WS_NSUM   = 16;                           // 8 slots, stride 32 floats (128B apart)
constexpr int WS_COUNTS = 16 + 8 * 32;                  // 272 (header ends here)
constexpr int WS_EMBSUM = WS_COUNTS + K_CODE;
constexpr int WS_WHI    = WS_EMBSUM + K_CODE * D_DIM;   // ushort[K*64] bf16 hi, XOR-swizzled
constexpr int WS_WLO    = WS_WHI + K_CODE * D_DIM / 2;  // ushort[K*64] bf16 lo, XOR-swizzled
constexpr int WS_CNF    = WS_WLO + K_CODE * D_DIM / 2;  // float[K]: ||c||^2 + 64 (exact f32)

typedef __attribute__((ext_vector_type(16))) float floatx16;
typedef __attribute__((ext_vector_type(8)))  short short8;
typedef __attribute__((ext_vector_type(8)))  __bf16 bf16x8;

// SFINAE hedge: mfma bf16 builtin takes v8bf16 on newer clang, v8i16 on older.
template <typename T, typename = void> struct mfma_takes : std::false_type {};
template <typename T>
struct mfma_takes<T, std::void_t<decltype(__builtin_amdgcn_mfma_f32_32x32x16_bf16(
    std::declval<T>(), std::declval<T>(), std::declval<floatx16>(), 0, 0, 0))>>
    : std::true_type {};

__device__ __forceinline__ floatx16 MFMA(short8 a, short8 b, floatx16 c) {
  if constexpr (mfma_takes<bf16x8>::value) {
    return __builtin_amdgcn_mfma_f32_32x32x16_bf16(
        __builtin_bit_cast(bf16x8, a), __builtin_bit_cast(bf16x8, b), c, 0, 0, 0);
  } else {
    return __builtin_amdgcn_mfma_f32_32x32x16_bf16(a, b, c, 0, 0, 0);
  }
}

__device__ __forceinline__ unsigned short bf16rne(float x) {
  unsigned int u = __float_as_uint(x);
  return (unsigned short)((u + 0x7FFFu + ((u >> 16) & 1u)) >> 16);
}

// async global->LDS 16B DMA (HW writes LDS at wave-uniform dst + lane*16)
__device__ __forceinline__ void gload_lds16(const unsigned short* g, unsigned short* l) {
#if defined(__has_builtin) && __has_builtin(__builtin_amdgcn_global_load_lds)
  typedef __attribute__((address_space(1))) void gvoid;
  typedef __attribute__((address_space(3))) void lvoid;
  __builtin_amdgcn_global_load_lds((gvoid*)g, (lvoid*)l, 16, 0, 0);
#else
  *(uint4*)l = *(const uint4*)g;   // sync fallback (builtin exists on gfx950)
#endif
}

// ---------------------------------------------------------------------------
// Split W into bf16 hi/lo, stored XOR-SWIZZLED (granule g -> g^(k&7), stride
// 64 shorts) so global_load_lds's linear copy lands conflict-managed in LDS.
// Store ||c||^2 + 64 as exact f32. NSUM: one atomic per block into 8
// line-spread slots. Folds counts/embsum zeroing in.
__global__ void vq_prep(const float* __restrict__ w, const float* __restrict__ cs,
                        float* __restrict__ ws) {
  const int tid = threadIdx.x;
  const int gid = blockIdx.x * 256 + tid;   // 0 .. K*D-1
  ws[WS_EMBSUM + gid] = 0.0f;
  if (gid < K_CODE) ws[WS_COUNTS + gid] = 0.0f;

  const int d = tid & 63;                 // dim
  const int kw = tid >> 6;                // 0..3
  const int k = blockIdx.x * 4 + kw;
  const float v = w[(size_t)k * D_DIM + d];
  const unsigned short h = bf16rne(v);
  const float hf = __uint_as_float((unsigned int)h << 16);
  const unsigned short l = bf16rne(v - hf);
  unsigned short* whi = (unsigned short*)(ws + WS_WHI);
  unsigned short* wlo = (unsigned short*)(ws + WS_WLO);
  const int pos = k * D_DIM + (((d >> 3) ^ (k & 7)) * 8) + (d & 7);
  whi[pos] = h;
  wlo[pos] = l;
  float s = v * v;
#pragma unroll
  for (int m = 32; m >= 1; m >>= 1) s += __shfl_xor(s, m);
  __shared__ float csp[4];
  if (d == 0) {
    (ws + WS_CNF)[k] = s + 64.0f;
    csp[kw] = cs[k];
  }
  __syncthreads();
  if (tid == 0) {
    atomicAdd(ws + WS_NSUM + ((blockIdx.x & 7) << 5),
              DECAY * (csp[0] + csp[1] + csp[2] + csp[3]));
  }
}

// ---------------------------------------------------------------------------
// Fused split-bf16 MFMA distance + argmin + segment-sum scatter.
//
// R8: 16 WAVES/CU *AND* HALVED B RE-READ. Cross-round isolation: R4
// (16 waves/CU, 12 MFMA + 8 ds/stage) = 214us; R6/R7 (8 waves/CU, 24 MFMA +
// 8 ds/stage, 1 or 2 barrier domains) = 231/242us — barrier domains and
// chain-split are irrelevant; waves/CU is THE latency-hiding lever (m114
// implicit wave overlap). R6's halved B-read never paid because it halved
// occupancy at the same time (256-tok blocks -> grid 256 -> 1 block/CU).
//
// Resolve both: ONE 1024-thread block per CU = 16 waves = 4 token-groups
// (64 tok each) x 4 code-quarters (2048 codes each); 256 tok/block, grid
// 256 = 1 block/CU. Each wave runs R6's proven body (24 MFMA, two 12-deep
// chains, 8 ds_read_b128) over 64 stages of 32 codes. Bonuses vs R4: half
// the barriers (64), half the global->LDS DMA (codebook staged once per
// block, 256 blocks not 512).
//
// LDS 136KB: Wbuf[4 quarters][4 bufs][2 planes][32x64] = 128KB + merge 8KB
// (gfx950 has 160KB/CU; 128KB-LDS plain-HIP kernels are proven on-chip).
// launch_bounds(1024,4): 4 waves/EU -> 128-VGPR cap; R6 measured 92 for
// this body. WRITE_SIZE is the spill tripwire.
//
// Staging: stage = 32KB (4 quarters x 32 codes x 2 planes), 32 x 1KB
// segments; wave w moves t = 2w, 2w+1 (q=t>>3, plane=(t>>2)&1, seg=t&3).
// Pipeline safety (R4's proofs, re-derived): each fenced region issues
// exactly {2 DMA, 1 cnf} = 3 vm ops; vmcnt(3) at region s retires region
// s-1's ops, incl. the DMA pair for buf (s+1)&3, before barrier(s)
// publishes it block-wide — exactly what LOADBH(bh,(s+1)&3) needs.
// DMA(s+2) issues 2 stages ahead of its reads. 4 bufs: DMA target (s+2)&3
// never collides with live reads (s&3 bl, (s+1)&3 bh read-ahead) nor with
// stage s-1 stragglers ((s-1)&3 = (s+3)&3, distinct). Branchless wrap
// keeps vm-op counts uniform (tail DMAs land in dead buffers).
__global__ __launch_bounds__(1024, 4) void vq_argmin(
    const float* __restrict__ z, float* __restrict__ ws)
{
  __shared__ __align__(16) unsigned short Wbuf[4][4][2][32 * 64]; // [qtr][buf][plane]
  __shared__ float mind_s[4][256];
  __shared__ int   tok_s[4][256];

  const int tid  = threadIdx.x;
  const int w    = tid >> 6;    // wave 0..15
  const int lane = tid & 63;
  const int m    = lane & 31;   // A row (token) / B col (code) in tile
  const int h    = lane >> 5;   // k-half selector
  const int tgp  = w & 3;       // token-pair group (64 tokens)
  const int qw   = w >> 2;      // code quarter (2048 codes)
  const int tb   = blockIdx.x * 256;

  const unsigned short* whi = (const unsigned short*)(ws + WS_WHI);
  const unsigned short* wlo = (const unsigned short*)(ws + WS_WLO);
  const float*          cnf = ws + WS_CNF;

  // ---- A fragments: bf16 hi/lo split of -2*z for 2x32 token rows ----
  short8 ah_a[4], al_a[4], ah_b[4], al_b[4];
  float znorm_a = 0.f, znorm_b = 0.f;
  auto loadA = [&](int sub, short8* AH, short8* AL, float& zn) {
    const float* zrow =
        z + (size_t)(tb + tgp * 64 + sub * 32 + m) * D_DIM + 8 * h;
#pragma unroll
    for (int s4 = 0; s4 < 4; ++s4) {
      const float4 v0 = *(const float4*)(zrow + 16 * s4);
      const float4 v1 = *(const float4*)(zrow + 16 * s4 + 4);
      const float vals[8] = {v0.x, v0.y, v0.z, v0.w, v1.x, v1.y, v1.z, v1.w};
#pragma unroll
      for (int j = 0; j < 8; ++j) {
        const float x = vals[j];
        zn += x * x;
        const float y = -2.0f * x;
        const unsigned short hb = bf16rne(y);
        const float hf = __uint_as_float((unsigned int)hb << 16);
        const unsigned short lb = bf16rne(y - hf);
        AH[s4][j] = (short)hb;
        AL[s4][j] = (short)lb;
      }
    }
    zn += __shfl_xor(zn, 32);   // other k-half of the same token row
  };
  loadA(0, ah_a, al_a, znorm_a);
  loadA(1, ah_b, al_b, znorm_b);

  float kmin0[16], kmin1[16];
#pragma unroll
  for (int r = 0; r < 16; ++r) { kmin0[r] = 3.4e38f; kmin1[r] = 3.4e38f; }

  // ---- DMA staging: stage = 32 KB as 32 x 1KB segments; wave w moves
  // segments 2w, 2w+1. seg t: qtr=t>>3, plane=(t>>2)&1, quarter-seg=t&3.
  auto issueStage = [&](int sIdx, int bufIdx) {
#pragma unroll
    for (int i = 0; i < 2; ++i) {
      const int t = w * 2 + i;
      const int q = t >> 3, plane = (t >> 2) & 1, seg = t & 3;
      const unsigned short* src = (plane ? wlo : whi)
          + ((size_t)q * 2048 + (size_t)sIdx * 32) * D_DIM + seg * 512 + lane * 8;
      unsigned short* dst = &Wbuf[q][bufIdx][plane][seg * 512];  // wave-uniform
      gload_lds16(src, dst);
    }
  };

  // precomputed per-lane B read offsets (shorts) into the pre-swizzled rows
  int xoff[4];
#pragma unroll
  for (int s4 = 0; s4 < 4; ++s4) xoff[s4] = ((2 * s4 + h) ^ (m & 7)) * 8;
  const int mrow = m * 64;
  const int cbase = qw * 2048;

#define LOADBH(BH, BUF) do {                                          \
    const unsigned short* _p = &Wbuf[qw][(BUF)][0][mrow];             \
    BH[0] = *(const short8*)(_p + xoff[0]);                           \
    BH[1] = *(const short8*)(_p + xoff[1]);                           \
    BH[2] = *(const short8*)(_p + xoff[2]);                           \
    BH[3] = *(const short8*)(_p + xoff[3]);                           \
  } while (0)

#define LOADBL(BL, BUF) do {                                          \
    const unsigned short* _p = &Wbuf[qw][(BUF)][1][mrow];             \
    BL[0] = *(const short8*)(_p + xoff[0]);                           \
    BL[1] = *(const short8*)(_p + xoff[1]);                           \
    BL[2] = *(const short8*)(_p + xoff[2]);                           \
    BL[3] = *(const short8*)(_p + xoff[3]);                           \
  } while (0)

  // ---- prologue: 2 stages of DMA, drain once, prime bh <- stage 0 ----
  issueStage(0, 0);
  issueStage(1, 1);
  float cn_cur = cnf[cbase + m];
  asm volatile("s_waitcnt vmcnt(0)" ::: "memory");
  __builtin_amdgcn_s_barrier();
  asm volatile("" ::: "memory");

  short8 bh[4], bl[4];
  LOADBH(bh, 0);

  for (int s = 0; s < 64; ++s) {
    // region s: issue exactly {2 DMA, 1 cnf} = 3 vm ops
    issueStage((s + 2) & 63, (s + 2) & 3);
    const float cn_next = cnf[cbase + ((s + 1) & 63) * 32 + m];
    asm volatile("s_waitcnt vmcnt(3)" ::: "memory");
    __builtin_amdgcn_s_barrier();
    asm volatile("" ::: "memory");

    LOADBL(bl, s & 3);                       // covered by the 16 bh-MFMAs

    floatx16 acc0, acc1;
#pragma unroll
    for (int r = 0; r < 16; ++r) { acc0[r] = cn_cur; acc1[r] = cn_cur; }

    __builtin_amdgcn_s_setprio(1);
    // G1: (-2zh).ch — two independent chains interleaved
    acc0 = MFMA(ah_a[0], bh[0], acc0); acc1 = MFMA(ah_b[0], bh[0], acc1);
    acc0 = MFMA(ah_a[1], bh[1], acc0); acc1 = MFMA(ah_b[1], bh[1], acc1);
    acc0 = MFMA(ah_a[2], bh[2], acc0); acc1 = MFMA(ah_b[2], bh[2], acc1);
    acc0 = MFMA(ah_a[3], bh[3], acc0); acc1 = MFMA(ah_b[3], bh[3], acc1);
    // G2: (-2zl).ch
    acc0 = MFMA(al_a[0], bh[0], acc0); acc1 = MFMA(al_b[0], bh[0], acc1);
    acc0 = MFMA(al_a[1], bh[1], acc0); acc1 = MFMA(al_b[1], bh[1], acc1);
    acc0 = MFMA(al_a[2], bh[2], acc0); acc1 = MFMA(al_b[2], bh[2], acc1);
    acc0 = MFMA(al_a[3], bh[3], acc0); acc1 = MFMA(al_b[3], bh[3], acc1);
    __builtin_amdgcn_s_setprio(0);

    LOADBH(bh, (s + 1) & 3);                 // WAR pins after all bh reads;
                                             // covered by bl-MFMAs+kmin+barrier
    __builtin_amdgcn_s_setprio(1);
    // G3: (-2zh).cl
    acc0 = MFMA(ah_a[0], bl[0], acc0); acc1 = MFMA(ah_b[0], bl[0], acc1);
    acc0 = MFMA(ah_a[1], bl[1], acc0); acc1 = MFMA(ah_b[1], bl[1], acc1);
    acc0 = MFMA(ah_a[2], bl[2], acc0); acc1 = MFMA(ah_b[2], bl[2], acc1);
    acc0 = MFMA(ah_a[3], bl[3], acc0); acc1 = MFMA(ah_b[3], bl[3], acc1);
    __builtin_amdgcn_s_setprio(0);

    // packed-key argmin: acc[r] > 0; low byte := stage id (0..63)
#pragma unroll
    for (int r = 0; r < 16; ++r) {
      kmin0[r] = fminf(kmin0[r],
          __uint_as_float((__float_as_uint(acc0[r]) & 0xFFFFFF00u) | (unsigned)s));
      kmin1[r] = fminf(kmin1[r],
          __uint_as_float((__float_as_uint(acc1[r]) & 0xFFFFFF00u) | (unsigned)s));
    }
    cn_cur = cn_next;
  }
#undef LOADBH
#undef LOADBL

  // ---- reduce over the 32 code-cols per row, carrying origin lane ----
#define REDUCE_WRITE(KM, SUB, ZN) do {                                      \
    _Pragma("unroll")                                                       \
    for (int r = 0; r < 16; ++r) {                                          \
      float kv = KM[r];                                                     \
      int mo = m;                                                           \
      _Pragma("unroll")                                                     \
      for (int mm = 1; mm < 32; mm <<= 1) {                                 \
        const float ov = __shfl_xor(kv, mm);                                \
        const int   om = __shfl_xor(mo, mm);                                \
        if (ov < kv || (ov == kv && om < mo)) { kv = ov; mo = om; }         \
      }                                                                     \
      const int mr = (r & 3) + 8 * (r >> 2) + 4 * h;                        \
      if (m == mr) {                                                        \
        const unsigned int kb = __float_as_uint(kv);                        \
        const int trow = tgp * 64 + (SUB) * 32 + mr;                        \
        tok_s[qw][trow] = qw * 2048 + (int)(kb & 0xFFu) * 32 + mo;          \
        mind_s[qw][trow] = __uint_as_float(kb & 0xFFFFFF00u) - 64.0f + (ZN);\
      }                                                                     \
    }                                                                       \
  } while (0)

  REDUCE_WRITE(kmin0, 0, znorm_a);
  REDUCE_WRITE(kmin1, 1, znorm_b);
#undef REDUCE_WRITE
  __syncthreads();

  float* counts = ws + WS_COUNTS;
  float* embsum = ws + WS_EMBSUM;

  // merge code-quarters (sequential strict '<' keeps lowest quarter on
  // ties; within a quarter the packed key already encodes (stage, lane) =
  // ascending code order), qe partial + counts
  if (tid < 256) {
    float dm = mind_s[0][tid];
    int   im = tok_s[0][tid];
#pragma unroll
    for (int q = 1; q < 4; ++q) {
      const float dq = mind_s[q][tid];
      const int   iq = tok_s[q][tid];
      if (dq < dm) { dm = dq; im = iq; }
    }
    tok_s[0][tid] = im;
    float qe = dm;
#pragma unroll
    for (int mm = 32; mm >= 1; mm >>= 1) qe += __shfl_xor(qe, mm);
    if ((tid & 63) == 0) atomicAdd(ws + WS_QE, qe);
    atomicAdd(&counts[im], 1.0f);
  }
  __syncthreads();

  // segment-sum of z: wave-coalesced atomics (64 consecutive floats/instr)
#pragma unroll 4
  for (int t = 0; t < 16; ++t) {
    const int row = w * 16 + t;
    const int tk = tok_s[0][row];
    const float zv = z[(size_t)(tb + row) * D_DIM + lane];
    atomicAdd(&embsum[(size_t)tk * D_DIM + lane], zv);
  }
}

// ---------------------------------------------------------------------------
// Fused finalize: n = 0.9*sum(cs) + 0.1*N_TOK is precomputed by vq_prep
// (sum(counts) == N_TOK exactly), so ncs/nea/weight all finalize in one pass.
__global__ void vq_finalize(const float* __restrict__ cluster_size,
                            const float* __restrict__ embed_avg,
                            const float* __restrict__ ws, float* __restrict__ out)
{
  const int idx = blockIdx.x * 256 + threadIdx.x;   // over K*D
  const int k = idx >> 6;
  const float ncs = cluster_size[k] * DECAY + OMD * ws[WS_COUNTS + k];
  const float nea = embed_avg[idx] * DECAY + OMD * ws[WS_EMBSUM + idx];
  out[OUT_EA + idx] = nea;
  float n = OMD * (float)N_TOK;
#pragma unroll
  for (int i = 0; i < 8; ++i) n += ws[WS_NSUM + (i << 5)];
  const float sm = (ncs + EPS) / (n + K_CODE * EPS) * n;
  out[OUT_W + idx] = nea / sm;
  if ((idx & 63) == 0) out[OUT_CS + k] = ncs;
  if (idx == 0) out[OUT_QE] = ws[WS_QE] * (1.0f / N_TOK);
}

// ---------------------------------------------------------------------------
extern "C" void kernel_launch(void* const* d_in, const int* in_sizes, int n_in,
                              void* d_out, int out_size, void* d_ws, size_t ws_size,
                              hipStream_t stream) {
  const float* z  = (const float*)d_in[0];
  const float* w  = (const float*)d_in[1];
  const float* cs = (const float*)d_in[2];
  const float* ea = (const float*)d_in[3];
  float* out = (float*)d_out;
  float* ws  = (float*)d_ws;

  // header only (QE + NSUM slots); counts/embsum zeroing folded into vq_prep
  (void)hipMemsetAsync(d_ws, 0, (size_t)WS_COUNTS * sizeof(float), stream);

  vq_prep<<<K_CODE / 4, 256, 0, stream>>>(w, cs, ws);
  vq_argmin<<<N_TOK / 256, 1024, 0, stream>>>(z, ws);
  vq_finalize<<<K_CODE * D_DIM / 256, 256, 0, stream>>>(cs, ea, ws, out);
}

// Round 9
// 295.323 us; speedup vs baseline: 3.1497x; 3.1497x over previous
//
#include <hip/hip_runtime.h>
#include <type_traits>

#define N_TOK 65536
#define K_CODE 8192
#define D_DIM 64

constexpr float DECAY = 0.9f;
constexpr float OMD = 0.1f;   // 1 - DECAY
constexpr float EPS = 1e-5f;

// ---- output layout (floats), per reference return order ----
constexpr int OUT_QE = 0;
constexpr int OUT_W  = 1;
constexpr int OUT_CS = 1 + K_CODE * D_DIM;
constexpr int OUT_EA = OUT_CS + K_CODE;

// ---- workspace layout (floats) ----
constexpr int WS_QE     = 0;
constexpr int WS_NSUM   = 16;                           // 8 slots, stride 32 floats (128B apart)
constexpr int WS_COUNTS = 16 + 8 * 32;                  // 272 (header ends here)
constexpr int WS_EMBSUM = WS_COUNTS + K_CODE;
constexpr int WS_WHI    = WS_EMBSUM + K_CODE * D_DIM;   // ushort[K*64] bf16 hi, XOR-swizzled
constexpr int WS_WLO    = WS_WHI + K_CODE * D_DIM / 2;  // ushort[K*64] bf16 lo, XOR-swizzled
constexpr int WS_CNF    = WS_WLO + K_CODE * D_DIM / 2;  // float[K]: ||c||^2 + 64 (exact f32)

typedef __attribute__((ext_vector_type(16))) float floatx16;
typedef __attribute__((ext_vector_type(8)))  short short8;
typedef __attribute__((ext_vector_type(8)))  __bf16 bf16x8;

// SFINAE hedge: mfma bf16 builtin takes v8bf16 on newer clang, v8i16 on older.
template <typename T, typename = void> struct mfma_takes : std::false_type {};
template <typename T>
struct mfma_takes<T, std::void_t<decltype(__builtin_amdgcn_mfma_f32_32x32x16_bf16(
    std::declval<T>(), std::declval<T>(), std::declval<floatx16>(), 0, 0, 0))>>
    : std::true_type {};

__device__ __forceinline__ floatx16 MFMA(short8 a, short8 b, floatx16 c) {
  if constexpr (mfma_takes<bf16x8>::value) {
    return __builtin_amdgcn_mfma_f32_32x32x16_bf16(
        __builtin_bit_cast(bf16x8, a), __builtin_bit_cast(bf16x8, b), c, 0, 0, 0);
  } else {
    return __builtin_amdgcn_mfma_f32_32x32x16_bf16(a, b, c, 0, 0, 0);
  }
}

__device__ __forceinline__ unsigned short bf16rne(float x) {
  unsigned int u = __float_as_uint(x);
  return (unsigned short)((u + 0x7FFFu + ((u >> 16) & 1u)) >> 16);
}

// async global->LDS 16B DMA (HW writes LDS at wave-uniform dst + lane*16)
__device__ __forceinline__ void gload_lds16(const unsigned short* g, unsigned short* l) {
#if defined(__has_builtin) && __has_builtin(__builtin_amdgcn_global_load_lds)
  typedef __attribute__((address_space(1))) void gvoid;
  typedef __attribute__((address_space(3))) void lvoid;
  __builtin_amdgcn_global_load_lds((gvoid*)g, (lvoid*)l, 16, 0, 0);
#else
  *(uint4*)l = *(const uint4*)g;   // sync fallback (builtin exists on gfx950)
#endif
}

// ---------------------------------------------------------------------------
// Split W into bf16 hi/lo, stored XOR-SWIZZLED (granule g -> g^(k&7), stride
// 64 shorts) so global_load_lds's linear copy lands conflict-managed in LDS.
// Store ||c||^2 + 64 as exact f32. NSUM: one atomic per block into 8
// line-spread slots. Folds counts/embsum zeroing in (host memset = header
// only; stream order memset -> prep -> argmin keeps NSUM atomics safe).
__global__ void vq_prep(const float* __restrict__ w, const float* __restrict__ cs,
                        float* __restrict__ ws) {
  const int tid = threadIdx.x;
  const int gid = blockIdx.x * 256 + tid;   // 0 .. K*D-1
  ws[WS_EMBSUM + gid] = 0.0f;
  if (gid < K_CODE) ws[WS_COUNTS + gid] = 0.0f;

  const int d = tid & 63;                 // dim
  const int kw = tid >> 6;                // 0..3
  const int k = blockIdx.x * 4 + kw;
  const float v = w[(size_t)k * D_DIM + d];
  const unsigned short h = bf16rne(v);
  const float hf = __uint_as_float((unsigned int)h << 16);
  const unsigned short l = bf16rne(v - hf);
  unsigned short* whi = (unsigned short*)(ws + WS_WHI);
  unsigned short* wlo = (unsigned short*)(ws + WS_WLO);
  const int pos = k * D_DIM + (((d >> 3) ^ (k & 7)) * 8) + (d & 7);
  whi[pos] = h;
  wlo[pos] = l;
  float s = v * v;
#pragma unroll
  for (int m = 32; m >= 1; m >>= 1) s += __shfl_xor(s, m);
  __shared__ float csp[4];
  if (d == 0) {
    (ws + WS_CNF)[k] = s + 64.0f;
    csp[kw] = cs[k];
  }
  __syncthreads();
  if (tid == 0) {
    atomicAdd(ws + WS_NSUM + ((blockIdx.x & 7) << 5),
              DECAY * (csp[0] + csp[1] + csp[2] + csp[3]));
  }
}

// ---------------------------------------------------------------------------
// Fused split-bf16 MFMA distance + argmin + segment-sum scatter.
//
// R9: R4 STRUCTURE + 2-WAY CHAIN SPLIT. Register-file accounting across
// R2..R8 (cap ~256/launch_bounds_arg2 arch VGPRs; waves/SIMD =
// floor(512/(VGPR+AGPR))): the 64-tok/wave body (~170 regs) can never
// co-exist with 16 waves/CU — R6/R7's low occupancy was a register wall.
// The 32-tok/wave body (~110-125 regs) at 16 waves/CU (R4, 214us) is the
// only shape fitting both, so the remaining lever is its per-wave critical
// path: 12 DEPENDENT MFMAs (~70cy dep latency each ~ 840cy serial/stage).
// MfmaUtil 45% ~= 4 waves/SIMD x (387cy issue / ~860cy window) — chain-
// latency-bound. Split 12 -> 2 chains of 6 (accA init cn-splat carries
// G1 + 2 bl-products; accB starts kZero carries G2 + 2 bl-products; summed
// before kmin). R7 proved this re-association bit-reproduces absmax
// 0.4335938. Cost: +16 AGPR (~122 unified <= 128, 4 waves/SIMD preserved;
// WRITE_SIZE is the spill tripwire) + 16 adds/stage.
//
// Block = 8 waves = 4 token-groups(32 tok) x 2 code-halves; 128 tok/block;
// grid 512 = 2 blocks/CU = 16 waves/CU = 4 waves/SIMD.
//
// Body schedule (R4's proven read-ahead): bl(s) ds_reads issue first,
// covered by the 8 bh-consuming MFMAs; bh(s+1) ds_read sits after them
// (register WAR pins it), covered by the 4 bl-MFMAs + sum + kmin + barrier.
//
// Pipeline safety (R4's proofs): each fenced region issues exactly
// {2 DMA, 1 cnf} = 3 vm ops; vmcnt(3) at region s retires region s-1's ops
// incl. DMA(s+1) — what LOADBH(bh,(s+1)&3) needs (own retire + barrier =
// cross-wave visibility). DMA(s+2) issues 2 stages ahead. 4 bufs: buf b's
// reads complete (in-order issue => data in regs) before that wave passes
// the next barrier; the overwriting DMA is 2+ barriers later => no race.
// Branchless wrap keeps vm-op counts uniform (tail DMAs land dead).
__global__ __launch_bounds__(512, 4) void vq_argmin(
    const float* __restrict__ z, float* __restrict__ ws)
{
  __shared__ __align__(16) unsigned short Wbuf[2][4][2][32 * 64]; // [half][buf][plane]
  __shared__ float mind_s[2][128];
  __shared__ int   tok_s[2][128];

  const int tid  = threadIdx.x;
  const int w    = tid >> 6;    // wave 0..7
  const int lane = tid & 63;
  const int m    = lane & 31;   // A row (token) / B col (code) in tile
  const int h    = lane >> 5;   // k-half selector
  const int tg   = w & 3;       // token group (32 tokens)
  const int hw   = w >> 2;      // code half (4096 codes)
  const int tb   = blockIdx.x * 128;

  const unsigned short* whi = (const unsigned short*)(ws + WS_WHI);
  const unsigned short* wlo = (const unsigned short*)(ws + WS_WLO);
  const float*          cnf = ws + WS_CNF;

  // ---- A fragments: bf16 hi/lo split of -2*z for this wave's 32 rows ----
  short8 ah[4], al[4];
  float znorm = 0.f;
  {
    const float* zrow = z + (size_t)(tb + tg * 32 + m) * D_DIM + 8 * h;
#pragma unroll
    for (int s4 = 0; s4 < 4; ++s4) {
      const float4 v0 = *(const float4*)(zrow + 16 * s4);
      const float4 v1 = *(const float4*)(zrow + 16 * s4 + 4);
      const float vals[8] = {v0.x, v0.y, v0.z, v0.w, v1.x, v1.y, v1.z, v1.w};
#pragma unroll
      for (int j = 0; j < 8; ++j) {
        const float x = vals[j];
        znorm += x * x;
        const float y = -2.0f * x;
        const unsigned short hb = bf16rne(y);
        const float hf = __uint_as_float((unsigned int)hb << 16);
        const unsigned short lb = bf16rne(y - hf);
        ah[s4][j] = (short)hb;
        al[s4][j] = (short)lb;
      }
    }
    znorm += __shfl_xor(znorm, 32);   // other k-half of the same token row
  }

  float kmin[16];
#pragma unroll
  for (int r = 0; r < 16; ++r) kmin[r] = 3.4e38f;

  // ---- DMA staging: stage = 16 KB as 16 x 1KB segments; wave w moves
  // segments 2w, 2w+1. seg t: half=t>>3, plane=(t>>2)&1, quarter=t&3.
  auto issueStage = [&](int sIdx, int bufIdx) {
#pragma unroll
    for (int i = 0; i < 2; ++i) {
      const int t = w * 2 + i;
      const int half = t >> 3, plane = (t >> 2) & 1, seg = t & 3;
      const unsigned short* src = (plane ? wlo : whi)
          + ((size_t)half * 4096 + (size_t)sIdx * 32) * D_DIM + seg * 512 + lane * 8;
      unsigned short* dst = &Wbuf[half][bufIdx][plane][seg * 512];  // wave-uniform
      gload_lds16(src, dst);
    }
  };

  // precomputed per-lane B read offsets (shorts) into the pre-swizzled rows
  int xoff[4];
#pragma unroll
  for (int s4 = 0; s4 < 4; ++s4) xoff[s4] = ((2 * s4 + h) ^ (m & 7)) * 8;
  const int mrow = m * 64;
  const int cbase = hw * 4096;

#define LOADBH(BH, BUF) do {                                          \
    const unsigned short* _p = &Wbuf[hw][(BUF)][0][mrow];             \
    BH[0] = *(const short8*)(_p + xoff[0]);                           \
    BH[1] = *(const short8*)(_p + xoff[1]);                           \
    BH[2] = *(const short8*)(_p + xoff[2]);                           \
    BH[3] = *(const short8*)(_p + xoff[3]);                           \
  } while (0)

#define LOADBL(BL, BUF) do {                                          \
    const unsigned short* _p = &Wbuf[hw][(BUF)][1][mrow];             \
    BL[0] = *(const short8*)(_p + xoff[0]);                           \
    BL[1] = *(const short8*)(_p + xoff[1]);                           \
    BL[2] = *(const short8*)(_p + xoff[2]);                           \
    BL[3] = *(const short8*)(_p + xoff[3]);                           \
  } while (0)

  // ---- prologue: 2 stages of DMA, drain once, prime bh <- stage 0 ----
  issueStage(0, 0);
  issueStage(1, 1);
  float cn_cur = cnf[cbase + m];
  asm volatile("s_waitcnt vmcnt(0)" ::: "memory");
  __builtin_amdgcn_s_barrier();
  asm volatile("" ::: "memory");

  short8 bh[4], bl[4];
  LOADBH(bh, 0);
  const floatx16 kZero = {};

  for (int s = 0; s < 128; ++s) {
    // region s: issue exactly {2 DMA, 1 cnf} = 3 vm ops (branchless wrap
    // keeps the count uniform; tail DMAs land in dead buffers)
    issueStage((s + 2) & 127, (s + 2) & 3);
    const float cn_next = cnf[cbase + ((s + 1) & 127) * 32 + m];
    asm volatile("s_waitcnt vmcnt(3)" ::: "memory");
    __builtin_amdgcn_s_barrier();
    asm volatile("" ::: "memory");

    LOADBL(bl, s & 3);                       // covered by the 8 bh-MFMAs

    floatx16 cnv;
#pragma unroll
    for (int r = 0; r < 16; ++r) cnv[r] = cn_cur;

    floatx16 A0, B0;
    __builtin_amdgcn_s_setprio(1);
    // bh-consuming MFMAs: two independent 4-deep prefixes
    A0 = MFMA(ah[0], bh[0], cnv);   B0 = MFMA(al[0], bh[0], kZero);
    A0 = MFMA(ah[1], bh[1], A0);    B0 = MFMA(al[1], bh[1], B0);
    A0 = MFMA(ah[2], bh[2], A0);    B0 = MFMA(al[2], bh[2], B0);
    A0 = MFMA(ah[3], bh[3], A0);    B0 = MFMA(al[3], bh[3], B0);
    __builtin_amdgcn_s_setprio(0);

    LOADBH(bh, (s + 1) & 3);                 // WAR pins after all bh reads;
                                             // covered by bl-MFMAs+sum+kmin
    __builtin_amdgcn_s_setprio(1);
    // bl-products, 2 per chain (chain depth 6 each)
    A0 = MFMA(ah[0], bl[0], A0);    B0 = MFMA(ah[2], bl[2], B0);
    A0 = MFMA(ah[1], bl[1], A0);    B0 = MFMA(ah[3], bl[3], B0);
    __builtin_amdgcn_s_setprio(0);

    // packed-key argmin on A0+B0: value > 0; low byte := stage id
#pragma unroll
    for (int r = 0; r < 16; ++r) {
      const float v0 = A0[r] + B0[r];
      kmin[r] = fminf(kmin[r],
          __uint_as_float((__float_as_uint(v0) & 0xFFFFFF00u) | (unsigned)s));
    }
    cn_cur = cn_next;
  }
#undef LOADBH
#undef LOADBL

  // ---- reduce over the 32 code-cols per row, carrying origin lane ----
#pragma unroll
  for (int r = 0; r < 16; ++r) {
    float kv = kmin[r];
    int mo = m;
#pragma unroll
    for (int mm = 1; mm < 32; mm <<= 1) {
      const float ov = __shfl_xor(kv, mm);
      const int   om = __shfl_xor(mo, mm);
      if (ov < kv || (ov == kv && om < mo)) { kv = ov; mo = om; }
    }
    // C/D layout: row = (r&3) + 8*(r>>2) + 4*h. One writer lane per row.
    const int mr = (r & 3) + 8 * (r >> 2) + 4 * h;
    if (m == mr) {
      const unsigned int kb = __float_as_uint(kv);
      tok_s[hw][tg * 32 + mr] = hw * 4096 + (int)(kb & 0xFFu) * 32 + mo;
      mind_s[hw][tg * 32 + mr] =
          __uint_as_float(kb & 0xFFFFFF00u) - 64.0f + znorm;
    }
  }
  __syncthreads();

  float* counts = ws + WS_COUNTS;
  float* embsum = ws + WS_EMBSUM;

  // merge code-halves (strict '<' keeps half0 on ties), qe partial + counts
  if (tid < 128) {
    const float d0 = mind_s[0][tid], d1 = mind_s[1][tid];
    const int   i0 = tok_s[0][tid],  i1 = tok_s[1][tid];
    const bool t1 = d1 < d0;
    const float dm = t1 ? d1 : d0;
    const int   im = t1 ? i1 : i0;
    tok_s[0][tid] = im;
    float qe = dm;
#pragma unroll
    for (int mm = 32; mm >= 1; mm >>= 1) qe += __shfl_xor(qe, mm);
    if ((tid & 63) == 0) atomicAdd(ws + WS_QE, qe);
    atomicAdd(&counts[im], 1.0f);
  }
  __syncthreads();

  // segment-sum of z: wave-coalesced atomics (64 consecutive floats/instr)
#pragma unroll 4
  for (int t = 0; t < 16; ++t) {
    const int row = w * 16 + t;
    const int tk = tok_s[0][row];
    const float zv = z[(size_t)(tb + row) * D_DIM + lane];
    atomicAdd(&embsum[(size_t)tk * D_DIM + lane], zv);
  }
}

// ---------------------------------------------------------------------------
// Fused finalize: n = 0.9*sum(cs) + 0.1*N_TOK is precomputed by vq_prep
// (sum(counts) == N_TOK exactly), so ncs/nea/weight all finalize in one pass.
__global__ void vq_finalize(const float* __restrict__ cluster_size,
                            const float* __restrict__ embed_avg,
                            const float* __restrict__ ws, float* __restrict__ out)
{
  const int idx = blockIdx.x * 256 + threadIdx.x;   // over K*D
  const int k = idx >> 6;
  const float ncs = cluster_size[k] * DECAY + OMD * ws[WS_COUNTS + k];
  const float nea = embed_avg[idx] * DECAY + OMD * ws[WS_EMBSUM + idx];
  out[OUT_EA + idx] = nea;
  float n = OMD * (float)N_TOK;
#pragma unroll
  for (int i = 0; i < 8; ++i) n += ws[WS_NSUM + (i << 5)];
  const float sm = (ncs + EPS) / (n + K_CODE * EPS) * n;
  out[OUT_W + idx] = nea / sm;
  if ((idx & 63) == 0) out[OUT_CS + k] = ncs;
  if (idx == 0) out[OUT_QE] = ws[WS_QE] * (1.0f / N_TOK);
}

// ---------------------------------------------------------------------------
extern "C" void kernel_launch(void* const* d_in, const int* in_sizes, int n_in,
                              void* d_out, int out_size, void* d_ws, size_t ws_size,
                              hipStream_t stream) {
  const float* z  = (const float*)d_in[0];
  const float* w  = (const float*)d_in[1];
  const float* cs = (const float*)d_in[2];
  const float* ea = (const float*)d_in[3];
  float* out = (float*)d_out;
  float* ws  = (float*)d_ws;

  // header only (QE + NSUM slots); counts/embsum zeroing folded into vq_prep
  (void)hipMemsetAsync(d_ws, 0, (size_t)WS_COUNTS * sizeof(float), stream);

  vq_prep<<<K_CODE / 4, 256, 0, stream>>>(w, cs, ws);
  vq_argmin<<<N_TOK / 128, 512, 0, stream>>>(z, ws);
  vq_finalize<<<K_CODE * D_DIM / 256, 256, 0, stream>>>(cs, ea, ws, out);
}

// Round 10
// 279.503 us; speedup vs baseline: 3.3280x; 1.0566x over previous
//
#include <hip/hip_runtime.h>
#include <type_traits>

#define N_TOK 65536
#define K_CODE 8192
#define D_DIM 64

constexpr float DECAY = 0.9f;
constexpr float OMD = 0.1f;   // 1 - DECAY
constexpr float EPS = 1e-5f;

// ---- output layout (floats), per reference return order ----
constexpr int OUT_QE = 0;
constexpr int OUT_W  = 1;
constexpr int OUT_CS = 1 + K_CODE * D_DIM;
constexpr int OUT_EA = OUT_CS + K_CODE;

// ---- workspace layout (floats) ----
constexpr int WS_QE     = 0;
constexpr int WS_NSUM   = 16;                           // 8 slots, stride 32 floats (128B apart)
constexpr int WS_COUNTS = 16 + 8 * 32;                  // 272 (header ends here)
constexpr int WS_EMBSUM = WS_COUNTS + K_CODE;
constexpr int WS_WHI    = WS_EMBSUM + K_CODE * D_DIM;   // ushort[K*64] bf16 hi, XOR-swizzled
constexpr int WS_WLO    = WS_WHI + K_CODE * D_DIM / 2;  // ushort[K*64] bf16 lo, XOR-swizzled
constexpr int WS_CNF    = WS_WLO + K_CODE * D_DIM / 2;  // float[K]: ||c||^2 + 64 (exact f32)

typedef __attribute__((ext_vector_type(16))) float floatx16;
typedef __attribute__((ext_vector_type(8)))  short short8;
typedef __attribute__((ext_vector_type(8)))  __bf16 bf16x8;

// SFINAE hedge: mfma bf16 builtin takes v8bf16 on newer clang, v8i16 on older.
template <typename T, typename = void> struct mfma_takes : std::false_type {};
template <typename T>
struct mfma_takes<T, std::void_t<decltype(__builtin_amdgcn_mfma_f32_32x32x16_bf16(
    std::declval<T>(), std::declval<T>(), std::declval<floatx16>(), 0, 0, 0))>>
    : std::true_type {};

__device__ __forceinline__ floatx16 MFMA(short8 a, short8 b, floatx16 c) {
  if constexpr (mfma_takes<bf16x8>::value) {
    return __builtin_amdgcn_mfma_f32_32x32x16_bf16(
        __builtin_bit_cast(bf16x8, a), __builtin_bit_cast(bf16x8, b), c, 0, 0, 0);
  } else {
    return __builtin_amdgcn_mfma_f32_32x32x16_bf16(a, b, c, 0, 0, 0);
  }
}

__device__ __forceinline__ unsigned short bf16rne(float x) {
  unsigned int u = __float_as_uint(x);
  return (unsigned short)((u + 0x7FFFu + ((u >> 16) & 1u)) >> 16);
}

// async global->LDS 16B DMA (HW writes LDS at wave-uniform dst + lane*16)
__device__ __forceinline__ void gload_lds16(const unsigned short* g, unsigned short* l) {
#if defined(__has_builtin) && __has_builtin(__builtin_amdgcn_global_load_lds)
  typedef __attribute__((address_space(1))) void gvoid;
  typedef __attribute__((address_space(3))) void lvoid;
  __builtin_amdgcn_global_load_lds((gvoid*)g, (lvoid*)l, 16, 0, 0);
#else
  *(uint4*)l = *(const uint4*)g;   // sync fallback (builtin exists on gfx950)
#endif
}

// ---------------------------------------------------------------------------
// Split W into bf16 hi/lo, stored XOR-SWIZZLED (granule g -> g^(k&7), stride
// 64 shorts) so global_load_lds's linear copy lands conflict-managed in LDS.
// Store ||c||^2 + 64 as exact f32. NSUM: one atomic per block into 8
// line-spread slots. Folds counts/embsum zeroing in (host memset = header
// only; stream order memset -> prep -> argmin keeps NSUM atomics safe).
__global__ void vq_prep(const float* __restrict__ w, const float* __restrict__ cs,
                        float* __restrict__ ws) {
  const int tid = threadIdx.x;
  const int gid = blockIdx.x * 256 + tid;   // 0 .. K*D-1
  ws[WS_EMBSUM + gid] = 0.0f;
  if (gid < K_CODE) ws[WS_COUNTS + gid] = 0.0f;

  const int d = tid & 63;                 // dim
  const int kw = tid >> 6;                // 0..3
  const int k = blockIdx.x * 4 + kw;
  const float v = w[(size_t)k * D_DIM + d];
  const unsigned short h = bf16rne(v);
  const float hf = __uint_as_float((unsigned int)h << 16);
  const unsigned short l = bf16rne(v - hf);
  unsigned short* whi = (unsigned short*)(ws + WS_WHI);
  unsigned short* wlo = (unsigned short*)(ws + WS_WLO);
  const int pos = k * D_DIM + (((d >> 3) ^ (k & 7)) * 8) + (d & 7);
  whi[pos] = h;
  wlo[pos] = l;
  float s = v * v;
#pragma unroll
  for (int m = 32; m >= 1; m >>= 1) s += __shfl_xor(s, m);
  __shared__ float csp[4];
  if (d == 0) {
    (ws + WS_CNF)[k] = s + 64.0f;
    csp[kw] = cs[k];
  }
  __syncthreads();
  if (tid == 0) {
    atomicAdd(ws + WS_NSUM + ((blockIdx.x & 7) << 5),
              DECAY * (csp[0] + csp[1] + csp[2] + csp[3]));
  }
}

// ---------------------------------------------------------------------------
// Fused split-bf16 MFMA distance + argmin + segment-sum scatter.
//
// R10: R4 + FULL-STAGE READ-AHEAD FOR BOTH B PLANES (register-neutral).
// R9 refuted chain-latency as the binder (split 12->2x6: 228us vs R4 214).
// Remaining model: the CU-SHARED LDS read pipe is ~2300 cyc/CU-stage (16
// waves x 8 b128 x 12cy + 513 conflict + 256 DMA-write) = 57% of the 4026
// wall; the 1.75x gap is queue wait — R4 reads bl(s) at stage START and
// consumes it at G3 MID-STAGE, so each wave's bl sits behind ~124 reads of
// the post-barrier burst (~1000cy lgkm stall at G3, every stage).
// Fix: bl is dead after G3, so read bl(s+1) AFTER G3 (register WAR pins
// it) exactly like bh(s+1) after G2. Every stage then opens with all 12
// MFMA operands in registers; each LDS read gets a full-stage (~2000cy)
// landing window. Same registers, same liveness width, same math order as
// R4 => absmax must reproduce 0.4335938 bit-identically.
//
// Block = 8 waves = 4 token-groups(32 tok) x 2 code-halves; 128 tok/block;
// grid 512 = 2 blocks/CU = 16 waves/CU = 4 waves/SIMD (the proven occupancy
// cell; register wall caps tokens/wave at 32 — R2/R6/R7/R8 lessons).
//
// Pipeline safety (R4's proofs): each fenced region issues exactly
// {2 DMA, 1 cnf} = 3 vm ops; vmcnt(3) at region s retires region s-1's ops
// incl. DMA(s+1); barrier(s) publishes buf (s+1)&3 block-wide — the same
// guarantee both LOADBH(bh,(s+1)&3) and LOADBL(bl,(s+1)&3) rely on.
// DMA(s+2) issues 2 stages ahead. 4 bufs: buf (s+1)&3 is read during stage
// s, its overwriting DMA issues at region s+3 (2+ barriers later) => no
// race. Branchless wrap keeps vm-op counts uniform (tail reads/DMAs land
// in dead buffers).
__global__ __launch_bounds__(512, 4) void vq_argmin(
    const float* __restrict__ z, float* __restrict__ ws)
{
  __shared__ __align__(16) unsigned short Wbuf[2][4][2][32 * 64]; // [half][buf][plane]
  __shared__ float mind_s[2][128];
  __shared__ int   tok_s[2][128];

  const int tid  = threadIdx.x;
  const int w    = tid >> 6;    // wave 0..7
  const int lane = tid & 63;
  const int m    = lane & 31;   // A row (token) / B col (code) in tile
  const int h    = lane >> 5;   // k-half selector
  const int tg   = w & 3;       // token group (32 tokens)
  const int hw   = w >> 2;      // code half (4096 codes)
  const int tb   = blockIdx.x * 128;

  const unsigned short* whi = (const unsigned short*)(ws + WS_WHI);
  const unsigned short* wlo = (const unsigned short*)(ws + WS_WLO);
  const float*          cnf = ws + WS_CNF;

  // ---- A fragments: bf16 hi/lo split of -2*z for this wave's 32 rows ----
  short8 ah[4], al[4];
  float znorm = 0.f;
  {
    const float* zrow = z + (size_t)(tb + tg * 32 + m) * D_DIM + 8 * h;
#pragma unroll
    for (int s4 = 0; s4 < 4; ++s4) {
      const float4 v0 = *(const float4*)(zrow + 16 * s4);
      const float4 v1 = *(const float4*)(zrow + 16 * s4 + 4);
      const float vals[8] = {v0.x, v0.y, v0.z, v0.w, v1.x, v1.y, v1.z, v1.w};
#pragma unroll
      for (int j = 0; j < 8; ++j) {
        const float x = vals[j];
        znorm += x * x;
        const float y = -2.0f * x;
        const unsigned short hb = bf16rne(y);
        const float hf = __uint_as_float((unsigned int)hb << 16);
        const unsigned short lb = bf16rne(y - hf);
        ah[s4][j] = (short)hb;
        al[s4][j] = (short)lb;
      }
    }
    znorm += __shfl_xor(znorm, 32);   // other k-half of the same token row
  }

  float kmin[16];
#pragma unroll
  for (int r = 0; r < 16; ++r) kmin[r] = 3.4e38f;

  // ---- DMA staging: stage = 16 KB as 16 x 1KB segments; wave w moves
  // segments 2w, 2w+1. seg t: half=t>>3, plane=(t>>2)&1, quarter=t&3.
  auto issueStage = [&](int sIdx, int bufIdx) {
#pragma unroll
    for (int i = 0; i < 2; ++i) {
      const int t = w * 2 + i;
      const int half = t >> 3, plane = (t >> 2) & 1, seg = t & 3;
      const unsigned short* src = (plane ? wlo : whi)
          + ((size_t)half * 4096 + (size_t)sIdx * 32) * D_DIM + seg * 512 + lane * 8;
      unsigned short* dst = &Wbuf[half][bufIdx][plane][seg * 512];  // wave-uniform
      gload_lds16(src, dst);
    }
  };

  // precomputed per-lane B read offsets (shorts) into the pre-swizzled rows
  int xoff[4];
#pragma unroll
  for (int s4 = 0; s4 < 4; ++s4) xoff[s4] = ((2 * s4 + h) ^ (m & 7)) * 8;
  const int mrow = m * 64;
  const int cbase = hw * 4096;

#define LOADBH(BH, BUF) do {                                          \
    const unsigned short* _p = &Wbuf[hw][(BUF)][0][mrow];             \
    BH[0] = *(const short8*)(_p + xoff[0]);                           \
    BH[1] = *(const short8*)(_p + xoff[1]);                           \
    BH[2] = *(const short8*)(_p + xoff[2]);                           \
    BH[3] = *(const short8*)(_p + xoff[3]);                           \
  } while (0)

#define LOADBL(BL, BUF) do {                                          \
    const unsigned short* _p = &Wbuf[hw][(BUF)][1][mrow];             \
    BL[0] = *(const short8*)(_p + xoff[0]);                           \
    BL[1] = *(const short8*)(_p + xoff[1]);                           \
    BL[2] = *(const short8*)(_p + xoff[2]);                           \
    BL[3] = *(const short8*)(_p + xoff[3]);                           \
  } while (0)

  // ---- prologue: 2 stages of DMA, drain once, prime bh+bl <- stage 0 ----
  issueStage(0, 0);
  issueStage(1, 1);
  float cn_cur = cnf[cbase + m];
  asm volatile("s_waitcnt vmcnt(0)" ::: "memory");
  __builtin_amdgcn_s_barrier();
  asm volatile("" ::: "memory");

  short8 bh[4], bl[4];
  LOADBH(bh, 0);
  LOADBL(bl, 0);

  for (int s = 0; s < 128; ++s) {
    // region s: issue exactly {2 DMA, 1 cnf} = 3 vm ops (branchless wrap
    // keeps the count uniform; tail DMAs land in dead buffers)
    issueStage((s + 2) & 127, (s + 2) & 3);
    const float cn_next = cnf[cbase + ((s + 1) & 127) * 32 + m];
    asm volatile("s_waitcnt vmcnt(3)" ::: "memory");
    __builtin_amdgcn_s_barrier();
    asm volatile("" ::: "memory");

    // stage s: ALL operands already in registers — no LDS dep until G1(s+1)
    floatx16 acc;
#pragma unroll
    for (int r = 0; r < 16; ++r) acc[r] = cn_cur;

    __builtin_amdgcn_s_setprio(1);
    acc = MFMA(ah[0], bh[0], acc); acc = MFMA(ah[1], bh[1], acc);   // G1
    acc = MFMA(ah[2], bh[2], acc); acc = MFMA(ah[3], bh[3], acc);
    acc = MFMA(al[0], bh[0], acc); acc = MFMA(al[1], bh[1], acc);   // G2
    acc = MFMA(al[2], bh[2], acc); acc = MFMA(al[3], bh[3], acc);
    __builtin_amdgcn_s_setprio(0);

    LOADBH(bh, (s + 1) & 3);                 // WAR pins after G2; full-stage
                                             // landing window to G1(s+1)
    __builtin_amdgcn_s_setprio(1);
    acc = MFMA(ah[0], bl[0], acc); acc = MFMA(ah[1], bl[1], acc);   // G3
    acc = MFMA(ah[2], bl[2], acc); acc = MFMA(ah[3], bl[3], acc);
    __builtin_amdgcn_s_setprio(0);

    LOADBL(bl, (s + 1) & 3);                 // WAR pins after G3; full-stage
                                             // landing window to G3(s+1)

    // packed-key argmin: acc[r] > 0; low byte := stage id
#pragma unroll
    for (int r = 0; r < 16; ++r) {
      kmin[r] = fminf(kmin[r],
          __uint_as_float((__float_as_uint(acc[r]) & 0xFFFFFF00u) | (unsigned)s));
    }
    cn_cur = cn_next;
  }
#undef LOADBH
#undef LOADBL

  // ---- reduce over the 32 code-cols per row, carrying origin lane ----
#pragma unroll
  for (int r = 0; r < 16; ++r) {
    float kv = kmin[r];
    int mo = m;
#pragma unroll
    for (int mm = 1; mm < 32; mm <<= 1) {
      const float ov = __shfl_xor(kv, mm);
      const int   om = __shfl_xor(mo, mm);
      if (ov < kv || (ov == kv && om < mo)) { kv = ov; mo = om; }
    }
    // C/D layout: row = (r&3) + 8*(r>>2) + 4*h. One writer lane per row.
    const int mr = (r & 3) + 8 * (r >> 2) + 4 * h;
    if (m == mr) {
      const unsigned int kb = __float_as_uint(kv);
      tok_s[hw][tg * 32 + mr] = hw * 4096 + (int)(kb & 0xFFu) * 32 + mo;
      mind_s[hw][tg * 32 + mr] =
          __uint_as_float(kb & 0xFFFFFF00u) - 64.0f + znorm;
    }
  }
  __syncthreads();

  float* counts = ws + WS_COUNTS;
  float* embsum = ws + WS_EMBSUM;

  // merge code-halves (strict '<' keeps half0 on ties), qe partial + counts
  if (tid < 128) {
    const float d0 = mind_s[0][tid], d1 = mind_s[1][tid];
    const int   i0 = tok_s[0][tid],  i1 = tok_s[1][tid];
    const bool t1 = d1 < d0;
    const float dm = t1 ? d1 : d0;
    const int   im = t1 ? i1 : i0;
    tok_s[0][tid] = im;
    float qe = dm;
#pragma unroll
    for (int mm = 32; mm >= 1; mm >>= 1) qe += __shfl_xor(qe, mm);
    if ((tid & 63) == 0) atomicAdd(ws + WS_QE, qe);
    atomicAdd(&counts[im], 1.0f);
  }
  __syncthreads();

  // segment-sum of z: wave-coalesced atomics (64 consecutive floats/instr)
#pragma unroll 4
  for (int t = 0; t < 16; ++t) {
    const int row = w * 16 + t;
    const int tk = tok_s[0][row];
    const float zv = z[(size_t)(tb + row) * D_DIM + lane];
    atomicAdd(&embsum[(size_t)tk * D_DIM + lane], zv);
  }
}

// ---------------------------------------------------------------------------
// Fused finalize: n = 0.9*sum(cs) + 0.1*N_TOK is precomputed by vq_prep
// (sum(counts) == N_TOK exactly), so ncs/nea/weight all finalize in one pass.
__global__ void vq_finalize(const float* __restrict__ cluster_size,
                            const float* __restrict__ embed_avg,
                            const float* __restrict__ ws, float* __restrict__ out)
{
  const int idx = blockIdx.x * 256 + threadIdx.x;   // over K*D
  const int k = idx >> 6;
  const float ncs = cluster_size[k] * DECAY + OMD * ws[WS_COUNTS + k];
  const float nea = embed_avg[idx] * DECAY + OMD * ws[WS_EMBSUM + idx];
  out[OUT_EA + idx] = nea;
  float n = OMD * (float)N_TOK;
#pragma unroll
  for (int i = 0; i < 8; ++i) n += ws[WS_NSUM + (i << 5)];
  const float sm = (ncs + EPS) / (n + K_CODE * EPS) * n;
  out[OUT_W + idx] = nea / sm;
  if ((idx & 63) == 0) out[OUT_CS + k] = ncs;
  if (idx == 0) out[OUT_QE] = ws[WS_QE] * (1.0f / N_TOK);
}

// ---------------------------------------------------------------------------
extern "C" void kernel_launch(void* const* d_in, const int* in_sizes, int n_in,
                              void* d_out, int out_size, void* d_ws, size_t ws_size,
                              hipStream_t stream) {
  const float* z  = (const float*)d_in[0];
  const float* w  = (const float*)d_in[1];
  const float* cs = (const float*)d_in[2];
  const float* ea = (const float*)d_in[3];
  float* out = (float*)d_out;
  float* ws  = (float*)d_ws;

  // header only (QE + NSUM slots); counts/embsum zeroing folded into vq_prep
  (void)hipMemsetAsync(d_ws, 0, (size_t)WS_COUNTS * sizeof(float), stream);

  vq_prep<<<K_CODE / 4, 256, 0, stream>>>(w, cs, ws);
  vq_argmin<<<N_TOK / 128, 512, 0, stream>>>(z, ws);
  vq_finalize<<<K_CODE * D_DIM / 256, 256, 0, stream>>>(cs, ea, ws, out);
}

// Round 11
// 270.920 us; speedup vs baseline: 3.4334x; 1.0317x over previous
//
#include <hip/hip_runtime.h>
#include <type_traits>

#define N_TOK 65536
#define K_CODE 8192
#define D_DIM 64

constexpr float DECAY = 0.9f;
constexpr float OMD = 0.1f;   // 1 - DECAY
constexpr float EPS = 1e-5f;

// ---- output layout (floats), per reference return order ----
constexpr int OUT_QE = 0;
constexpr int OUT_W  = 1;
constexpr int OUT_CS = 1 + K_CODE * D_DIM;
constexpr int OUT_EA = OUT_CS + K_CODE;

// ---- workspace layout (floats) ----
constexpr int WS_QE     = 0;
constexpr int WS_NSUM   = 16;                           // 8 slots, stride 32 floats (128B apart)
constexpr int WS_COUNTS = 16 + 8 * 32;                  // 272 (header ends here)
constexpr int WS_EMBSUM = WS_COUNTS + K_CODE;
constexpr int WS_WHI    = WS_EMBSUM + K_CODE * D_DIM;   // ushort[K*64] bf16 hi, XOR-swizzled
constexpr int WS_WLO    = WS_WHI + K_CODE * D_DIM / 2;  // ushort[K*64] bf16 lo, XOR-swizzled
constexpr int WS_CNF    = WS_WLO + K_CODE * D_DIM / 2;  // float[K]: ||c||^2 + 64 (exact f32)

typedef __attribute__((ext_vector_type(16))) float floatx16;
typedef __attribute__((ext_vector_type(8)))  short short8;
typedef __attribute__((ext_vector_type(8)))  __bf16 bf16x8;

// SFINAE hedge: mfma bf16 builtin takes v8bf16 on newer clang, v8i16 on older.
template <typename T, typename = void> struct mfma_takes : std::false_type {};
template <typename T>
struct mfma_takes<T, std::void_t<decltype(__builtin_amdgcn_mfma_f32_32x32x16_bf16(
    std::declval<T>(), std::declval<T>(), std::declval<floatx16>(), 0, 0, 0))>>
    : std::true_type {};

__device__ __forceinline__ floatx16 MFMA(short8 a, short8 b, floatx16 c) {
  if constexpr (mfma_takes<bf16x8>::value) {
    return __builtin_amdgcn_mfma_f32_32x32x16_bf16(
        __builtin_bit_cast(bf16x8, a), __builtin_bit_cast(bf16x8, b), c, 0, 0, 0);
  } else {
    return __builtin_amdgcn_mfma_f32_32x32x16_bf16(a, b, c, 0, 0, 0);
  }
}

__device__ __forceinline__ unsigned short bf16rne(float x) {
  unsigned int u = __float_as_uint(x);
  return (unsigned short)((u + 0x7FFFu + ((u >> 16) & 1u)) >> 16);
}

// async global->LDS 16B DMA (HW writes LDS at wave-uniform dst + lane*16)
__device__ __forceinline__ void gload_lds16(const unsigned short* g, unsigned short* l) {
#if defined(__has_builtin) && __has_builtin(__builtin_amdgcn_global_load_lds)
  typedef __attribute__((address_space(1))) void gvoid;
  typedef __attribute__((address_space(3))) void lvoid;
  __builtin_amdgcn_global_load_lds((gvoid*)g, (lvoid*)l, 16, 0, 0);
#else
  *(uint4*)l = *(const uint4*)g;   // sync fallback (builtin exists on gfx950)
#endif
}

// ---------------------------------------------------------------------------
// Split W into bf16 hi/lo, stored XOR-SWIZZLED (granule g -> g^(k&7), stride
// 64 shorts) so global_load_lds's linear copy lands conflict-managed in LDS.
// Store ||c||^2 + 64 as exact f32. NSUM: one atomic per block into 8
// line-spread slots. Folds counts/embsum zeroing in (host memset = header
// only; stream order memset -> prep -> argmin keeps NSUM atomics safe).
__global__ void vq_prep(const float* __restrict__ w, const float* __restrict__ cs,
                        float* __restrict__ ws) {
  const int tid = threadIdx.x;
  const int gid = blockIdx.x * 256 + tid;   // 0 .. K*D-1
  ws[WS_EMBSUM + gid] = 0.0f;
  if (gid < K_CODE) ws[WS_COUNTS + gid] = 0.0f;

  const int d = tid & 63;                 // dim
  const int kw = tid >> 6;                // 0..3
  const int k = blockIdx.x * 4 + kw;
  const float v = w[(size_t)k * D_DIM + d];
  const unsigned short h = bf16rne(v);
  const float hf = __uint_as_float((unsigned int)h << 16);
  const unsigned short l = bf16rne(v - hf);
  unsigned short* whi = (unsigned short*)(ws + WS_WHI);
  unsigned short* wlo = (unsigned short*)(ws + WS_WLO);
  const int pos = k * D_DIM + (((d >> 3) ^ (k & 7)) * 8) + (d & 7);
  whi[pos] = h;
  wlo[pos] = l;
  float s = v * v;
#pragma unroll
  for (int m = 32; m >= 1; m >>= 1) s += __shfl_xor(s, m);
  __shared__ float csp[4];
  if (d == 0) {
    (ws + WS_CNF)[k] = s + 64.0f;
    csp[kw] = cs[k];
  }
  __syncthreads();
  if (tid == 0) {
    atomicAdd(ws + WS_NSUM + ((blockIdx.x & 7) << 5),
              DECAY * (csp[0] + csp[1] + csp[2] + csp[3]));
  }
}

// ---------------------------------------------------------------------------
// Fused split-bf16 MFMA distance + argmin + segment-sum scatter.
//
// R11: SPRINKLED WAR-FREEING READS (pipe overlap inside aligned phases).
// R10's accounting: block-stage wall 2025 cyc == LDS 1150 + MFMA 775 + VALU
// ~250 — ZERO pipe overlap. Mechanism: the barrier phase-aligns all 16
// waves, and program order puts all 8 bh-consuming MFMAs before any
// ds_read (reads are WAR-pinned behind the full consuming group). The CU
// alternates all-MFMA (~1000cy, LDS idle) / all-LDS (~1100cy, MFMA idle).
// Fix: pair the plane products — (ah_i*bh_i, al_i*bh_i) back-to-back — so
// bh_i dies after TWO MFMAs; its replacement read bh_i(s+1) issues right
// there. bl_i dies after its single G3 use; read follows it. Reads are now
// distributed across the whole MFMA phase -> LDS and MFMA pipes run
// concurrently. Zero extra registers; same 12 MFMAs; re-association shifts
// f32 rounding ~1ulp (R7/R9 precedent: absmax stable ~0.43).
// Also REMOVED setprio: m190 measured it null-to-negative on exactly this
// 2-phase structure; here it deprioritizes read-issuing waves, reinforcing
// the phase-lock.
//
// Block = 8 waves = 4 token-groups(32 tok) x 2 code-halves; 128 tok/block;
// grid 512 = 2 blocks/CU = 16 waves/CU = 4 waves/SIMD (proven occupancy
// cell; register wall caps tokens/wave at 32 — R2/R6/R7/R8 lessons).
//
// Pipeline safety (R4/R10 proofs, unchanged): each fenced region issues
// exactly {2 DMA, 1 cnf} = 3 vm ops; vmcnt(3) at region s retires region
// s-1's ops incl. DMA(s+1); barrier(s) publishes buf (s+1)&3 block-wide —
// the guarantee every bh/bl(s+1) read relies on. DMA(s+2) issues 2 stages
// ahead. 4 bufs: buf (s+1)&3 is read during stage s; its overwriting DMA
// issues at region s+3, 2+ barriers later => no race. Branchless wrap
// keeps vm-op counts uniform (tail reads/DMAs land in dead buffers).
__global__ __launch_bounds__(512, 4) void vq_argmin(
    const float* __restrict__ z, float* __restrict__ ws)
{
  __shared__ __align__(16) unsigned short Wbuf[2][4][2][32 * 64]; // [half][buf][plane]
  __shared__ float mind_s[2][128];
  __shared__ int   tok_s[2][128];

  const int tid  = threadIdx.x;
  const int w    = tid >> 6;    // wave 0..7
  const int lane = tid & 63;
  const int m    = lane & 31;   // A row (token) / B col (code) in tile
  const int h    = lane >> 5;   // k-half selector
  const int tg   = w & 3;       // token group (32 tokens)
  const int hw   = w >> 2;      // code half (4096 codes)
  const int tb   = blockIdx.x * 128;

  const unsigned short* whi = (const unsigned short*)(ws + WS_WHI);
  const unsigned short* wlo = (const unsigned short*)(ws + WS_WLO);
  const float*          cnf = ws + WS_CNF;

  // ---- A fragments: bf16 hi/lo split of -2*z for this wave's 32 rows ----
  short8 ah[4], al[4];
  float znorm = 0.f;
  {
    const float* zrow = z + (size_t)(tb + tg * 32 + m) * D_DIM + 8 * h;
#pragma unroll
    for (int s4 = 0; s4 < 4; ++s4) {
      const float4 v0 = *(const float4*)(zrow + 16 * s4);
      const float4 v1 = *(const float4*)(zrow + 16 * s4 + 4);
      const float vals[8] = {v0.x, v0.y, v0.z, v0.w, v1.x, v1.y, v1.z, v1.w};
#pragma unroll
      for (int j = 0; j < 8; ++j) {
        const float x = vals[j];
        znorm += x * x;
        const float y = -2.0f * x;
        const unsigned short hb = bf16rne(y);
        const float hf = __uint_as_float((unsigned int)hb << 16);
        const unsigned short lb = bf16rne(y - hf);
        ah[s4][j] = (short)hb;
        al[s4][j] = (short)lb;
      }
    }
    znorm += __shfl_xor(znorm, 32);   // other k-half of the same token row
  }

  float kmin[16];
#pragma unroll
  for (int r = 0; r < 16; ++r) kmin[r] = 3.4e38f;

  // ---- DMA staging: stage = 16 KB as 16 x 1KB segments; wave w moves
  // segments 2w, 2w+1. seg t: half=t>>3, plane=(t>>2)&1, quarter=t&3.
  auto issueStage = [&](int sIdx, int bufIdx) {
#pragma unroll
    for (int i = 0; i < 2; ++i) {
      const int t = w * 2 + i;
      const int half = t >> 3, plane = (t >> 2) & 1, seg = t & 3;
      const unsigned short* src = (plane ? wlo : whi)
          + ((size_t)half * 4096 + (size_t)sIdx * 32) * D_DIM + seg * 512 + lane * 8;
      unsigned short* dst = &Wbuf[half][bufIdx][plane][seg * 512];  // wave-uniform
      gload_lds16(src, dst);
    }
  };

  // precomputed per-lane B read offsets (shorts) into the pre-swizzled rows
  int xoff[4];
#pragma unroll
  for (int s4 = 0; s4 < 4; ++s4) xoff[s4] = ((2 * s4 + h) ^ (m & 7)) * 8;
  const int mrow = m * 64;
  const int cbase = hw * 4096;

#define RDH(BUF, I) (*(const short8*)&Wbuf[hw][(BUF)][0][mrow + xoff[(I)]])
#define RDL(BUF, I) (*(const short8*)&Wbuf[hw][(BUF)][1][mrow + xoff[(I)]])

  // ---- prologue: 2 stages of DMA, drain once, prime bh+bl <- stage 0 ----
  issueStage(0, 0);
  issueStage(1, 1);
  float cn_cur = cnf[cbase + m];
  asm volatile("s_waitcnt vmcnt(0)" ::: "memory");
  __builtin_amdgcn_s_barrier();
  asm volatile("" ::: "memory");

  short8 bh0 = RDH(0, 0), bh1 = RDH(0, 1), bh2 = RDH(0, 2), bh3 = RDH(0, 3);
  short8 bl0 = RDL(0, 0), bl1 = RDL(0, 1), bl2 = RDL(0, 2), bl3 = RDL(0, 3);

  for (int s = 0; s < 128; ++s) {
    // region s: issue exactly {2 DMA, 1 cnf} = 3 vm ops (branchless wrap
    // keeps the count uniform; tail DMAs land in dead buffers)
    issueStage((s + 2) & 127, (s + 2) & 3);
    const float cn_next = cnf[cbase + ((s + 1) & 127) * 32 + m];
    asm volatile("s_waitcnt vmcnt(3)" ::: "memory");
    __builtin_amdgcn_s_barrier();
    asm volatile("" ::: "memory");

    const int nb = (s + 1) & 3;

    floatx16 acc;
#pragma unroll
    for (int r = 0; r < 16; ++r) acc[r] = cn_cur;

    // pairwise plane products: bh_i dies after its 2 MFMAs -> its s+1
    // replacement read issues immediately (WAR-pinned, sprinkled through
    // the MFMA phase). bl_i dies after 1 MFMA; same pattern.
    acc = MFMA(ah[0], bh0, acc);
    acc = MFMA(al[0], bh0, acc);
    bh0 = RDH(nb, 0);
    acc = MFMA(ah[1], bh1, acc);
    acc = MFMA(al[1], bh1, acc);
    bh1 = RDH(nb, 1);
    acc = MFMA(ah[2], bh2, acc);
    acc = MFMA(al[2], bh2, acc);
    bh2 = RDH(nb, 2);
    acc = MFMA(ah[3], bh3, acc);
    acc = MFMA(al[3], bh3, acc);
    bh3 = RDH(nb, 3);
    acc = MFMA(ah[0], bl0, acc);
    bl0 = RDL(nb, 0);
    acc = MFMA(ah[1], bl1, acc);
    bl1 = RDL(nb, 1);
    acc = MFMA(ah[2], bl2, acc);
    bl2 = RDL(nb, 2);
    acc = MFMA(ah[3], bl3, acc);
    bl3 = RDL(nb, 3);

    // packed-key argmin: acc[r] > 0; low byte := stage id
#pragma unroll
    for (int r = 0; r < 16; ++r) {
      kmin[r] = fminf(kmin[r],
          __uint_as_float((__float_as_uint(acc[r]) & 0xFFFFFF00u) | (unsigned)s));
    }
    cn_cur = cn_next;
  }
#undef RDH
#undef RDL

  // ---- reduce over the 32 code-cols per row, carrying origin lane ----
#pragma unroll
  for (int r = 0; r < 16; ++r) {
    float kv = kmin[r];
    int mo = m;
#pragma unroll
    for (int mm = 1; mm < 32; mm <<= 1) {
      const float ov = __shfl_xor(kv, mm);
      const int   om = __shfl_xor(mo, mm);
      if (ov < kv || (ov == kv && om < mo)) { kv = ov; mo = om; }
    }
    // C/D layout: row = (r&3) + 8*(r>>2) + 4*h. One writer lane per row.
    const int mr = (r & 3) + 8 * (r >> 2) + 4 * h;
    if (m == mr) {
      const unsigned int kb = __float_as_uint(kv);
      tok_s[hw][tg * 32 + mr] = hw * 4096 + (int)(kb & 0xFFu) * 32 + mo;
      mind_s[hw][tg * 32 + mr] =
          __uint_as_float(kb & 0xFFFFFF00u) - 64.0f + znorm;
    }
  }
  __syncthreads();

  float* counts = ws + WS_COUNTS;
  float* embsum = ws + WS_EMBSUM;

  // merge code-halves (strict '<' keeps half0 on ties), qe partial + counts
  if (tid < 128) {
    const float d0 = mind_s[0][tid], d1 = mind_s[1][tid];
    const int   i0 = tok_s[0][tid],  i1 = tok_s[1][tid];
    const bool t1 = d1 < d0;
    const float dm = t1 ? d1 : d0;
    const int   im = t1 ? i1 : i0;
    tok_s[0][tid] = im;
    float qe = dm;
#pragma unroll
    for (int mm = 32; mm >= 1; mm >>= 1) qe += __shfl_xor(qe, mm);
    if ((tid & 63) == 0) atomicAdd(ws + WS_QE, qe);
    atomicAdd(&counts[im], 1.0f);
  }
  __syncthreads();

  // segment-sum of z: wave-coalesced atomics (64 consecutive floats/instr)
#pragma unroll 4
  for (int t = 0; t < 16; ++t) {
    const int row = w * 16 + t;
    const int tk = tok_s[0][row];
    const float zv = z[(size_t)(tb + row) * D_DIM + lane];
    atomicAdd(&embsum[(size_t)tk * D_DIM + lane], zv);
  }
}

// ---------------------------------------------------------------------------
// Fused finalize: n = 0.9*sum(cs) + 0.1*N_TOK is precomputed by vq_prep
// (sum(counts) == N_TOK exactly), so ncs/nea/weight all finalize in one pass.
__global__ void vq_finalize(const float* __restrict__ cluster_size,
                            const float* __restrict__ embed_avg,
                            const float* __restrict__ ws, float* __restrict__ out)
{
  const int idx = blockIdx.x * 256 + threadIdx.x;   // over K*D
  const int k = idx >> 6;
  const float ncs = cluster_size[k] * DECAY + OMD * ws[WS_COUNTS + k];
  const float nea = embed_avg[idx] * DECAY + OMD * ws[WS_EMBSUM + idx];
  out[OUT_EA + idx] = nea;
  float n = OMD * (float)N_TOK;
#pragma unroll
  for (int i = 0; i < 8; ++i) n += ws[WS_NSUM + (i << 5)];
  const float sm = (ncs + EPS) / (n + K_CODE * EPS) * n;
  out[OUT_W + idx] = nea / sm;
  if ((idx & 63) == 0) out[OUT_CS + k] = ncs;
  if (idx == 0) out[OUT_QE] = ws[WS_QE] * (1.0f / N_TOK);
}

// ---------------------------------------------------------------------------
extern "C" void kernel_launch(void* const* d_in, const int* in_sizes, int n_in,
                              void* d_out, int out_size, void* d_ws, size_t ws_size,
                              hipStream_t stream) {
  const float* z  = (const float*)d_in[0];
  const float* w  = (const float*)d_in[1];
  const float* cs = (const float*)d_in[2];
  const float* ea = (const float*)d_in[3];
  float* out = (float*)d_out;
  float* ws  = (float*)d_ws;

  // header only (QE + NSUM slots); counts/embsum zeroing folded into vq_prep
  (void)hipMemsetAsync(d_ws, 0, (size_t)WS_COUNTS * sizeof(float), stream);

  vq_prep<<<K_CODE / 4, 256, 0, stream>>>(w, cs, ws);
  vq_argmin<<<N_TOK / 128, 512, 0, stream>>>(z, ws);
  vq_finalize<<<K_CODE * D_DIM / 256, 256, 0, stream>>>(cs, ea, ws, out);
}